// Round 1
// baseline (185.275 us; speedup 1.0000x reference)
//
#include <hip/hip_runtime.h>
#include <math.h>

// Problem constants
#define NN 512
#define DD 512
#define NPAIRS 130816            // 512*511/2
#define TYPES_OFF 0              // [P,10] floats
#define ARGMAX_OFF 1308160      // [P] floats (indices as floats)
#define STRENGTH_OFF 1438976    // [P] floats

// ws layout (byte offsets):
//   ca_d  double[512][512]  @ 0          (features@cw1[:D]  + cb1, fp64)
//   cb_d  double[512][512]  @ 2097152    (features@cw1[D:],        fp64)
//   sa_f  float [512][256]  @ 4194304    (features@sw1[:D]  + sb1, fp32)
//   sb_f  float [512][256]  @ 4718592    (features@sw1[D:],        fp32)
//   cw2d  double[512][10]   @ 5242880
// total 5,283,840 bytes

__global__ void cvt_cw2_kernel(const float* __restrict__ cw2, double* __restrict__ cw2d) {
    int i = blockIdx.x * 256 + threadIdx.x;
    if (i < 5120) cw2d[i] = (double)cw2[i];
}

// C[512,1024] fp64 = F[512,512] @ [cw1[:512] | cw1[512:]]  (+cb1 on first half)
// 32x32 tiles, BK=32, 256 threads, 2x2 micro-tile, fp64 accumulate.
__global__ __launch_bounds__(256) void proj_c_kernel(
    const float* __restrict__ F, const float* __restrict__ cw1,
    const float* __restrict__ cb1, double* __restrict__ ca_d, double* __restrict__ cb_d)
{
    __shared__ double As[32 * 34];   // [k][m], pad 34
    __shared__ double Bs[32 * 34];   // [k][n], pad 34

    const int t = threadIdx.x;
    const int m0 = blockIdx.y * 32;
    const int n0 = blockIdx.x * 32;

    const float* Bp; const float* bias; double* outp; int coloff;
    if (n0 < 512) { Bp = cw1;             bias = cb1;     outp = ca_d; coloff = n0; }
    else          { Bp = cw1 + 512 * 512; bias = nullptr; outp = cb_d; coloff = n0 - 512; }

    const int ar  = t >> 3;   // 0..31 (row for A-stage, k-row for B-stage)
    const int akq = t & 7;    // 0..7  (float4 quad)
    const int ty  = t >> 4;   // 0..15
    const int tx  = t & 15;   // 0..15

    double acc00 = 0, acc01 = 0, acc10 = 0, acc11 = 0;

    for (int k0 = 0; k0 < 512; k0 += 32) {
        float4 fa = *(const float4*)&F [(m0 + ar) * 512 + k0 + akq * 4];
        float4 fb = *(const float4*)&Bp[(k0 + ar) * 512 + coloff + akq * 4];
        __syncthreads();
        // A transposed scatter: As[k][m]
        As[(akq * 4 + 0) * 34 + ar] = (double)fa.x;
        As[(akq * 4 + 1) * 34 + ar] = (double)fa.y;
        As[(akq * 4 + 2) * 34 + ar] = (double)fa.z;
        As[(akq * 4 + 3) * 34 + ar] = (double)fa.w;
        // B direct: Bs[k][n]
        double2* bd = (double2*)&Bs[ar * 34 + akq * 4];
        bd[0] = make_double2((double)fb.x, (double)fb.y);
        bd[1] = make_double2((double)fb.z, (double)fb.w);
        __syncthreads();
        #pragma unroll
        for (int kk = 0; kk < 32; ++kk) {
            double2 av = *(double2*)&As[kk * 34 + ty * 2];
            double2 bv = *(double2*)&Bs[kk * 34 + tx * 2];
            acc00 = fma(av.x, bv.x, acc00);
            acc01 = fma(av.x, bv.y, acc01);
            acc10 = fma(av.y, bv.x, acc10);
            acc11 = fma(av.y, bv.y, acc11);
        }
    }

    const int m = m0 + ty * 2;
    const int c = coloff + tx * 2;
    double b0 = bias ? (double)bias[c]     : 0.0;
    double b1 = bias ? (double)bias[c + 1] : 0.0;
    outp[(m + 0) * 512 + c + 0] = acc00 + b0;
    outp[(m + 0) * 512 + c + 1] = acc01 + b1;
    outp[(m + 1) * 512 + c + 0] = acc10 + b0;
    outp[(m + 1) * 512 + c + 1] = acc11 + b1;
}

// C[512,512] fp32 = F @ [sw1[:512] | sw1[512:]]  (+sb1 on first half); ldb=256
__global__ __launch_bounds__(256) void proj_s_kernel(
    const float* __restrict__ F, const float* __restrict__ sw1,
    const float* __restrict__ sb1, float* __restrict__ sa_f, float* __restrict__ sb_f)
{
    __shared__ float As[32 * 36];
    __shared__ float Bs[32 * 36];

    const int t = threadIdx.x;
    const int m0 = blockIdx.y * 32;
    const int n0 = blockIdx.x * 32;

    const float* Bp; const float* bias; float* outp; int coloff;
    if (n0 < 256) { Bp = sw1;             bias = sb1;     outp = sa_f; coloff = n0; }
    else          { Bp = sw1 + 512 * 256; bias = nullptr; outp = sb_f; coloff = n0 - 256; }

    const int ar  = t >> 3;
    const int akq = t & 7;
    const int ty  = t >> 4;
    const int tx  = t & 15;

    float acc00 = 0.f, acc01 = 0.f, acc10 = 0.f, acc11 = 0.f;

    for (int k0 = 0; k0 < 512; k0 += 32) {
        float4 fa = *(const float4*)&F [(m0 + ar) * 512 + k0 + akq * 4];
        float4 fb = *(const float4*)&Bp[(k0 + ar) * 256 + coloff + akq * 4];
        __syncthreads();
        As[(akq * 4 + 0) * 36 + ar] = fa.x;
        As[(akq * 4 + 1) * 36 + ar] = fa.y;
        As[(akq * 4 + 2) * 36 + ar] = fa.z;
        As[(akq * 4 + 3) * 36 + ar] = fa.w;
        *(float4*)&Bs[ar * 36 + akq * 4] = fb;   // 36%4==0 -> 16B aligned
        __syncthreads();
        #pragma unroll
        for (int kk = 0; kk < 32; ++kk) {
            float2 av = *(float2*)&As[kk * 36 + ty * 2];
            float2 bv = *(float2*)&Bs[kk * 36 + tx * 2];
            acc00 = fmaf(av.x, bv.x, acc00);
            acc01 = fmaf(av.x, bv.y, acc01);
            acc10 = fmaf(av.y, bv.x, acc10);
            acc11 = fmaf(av.y, bv.y, acc11);
        }
    }

    const int m = m0 + ty * 2;
    const int c = coloff + tx * 2;
    float b0 = bias ? bias[c]     : 0.f;
    float b1 = bias ? bias[c + 1] : 0.f;
    outp[(m + 0) * 256 + c + 0] = acc00 + b0;
    outp[(m + 0) * 256 + c + 1] = acc01 + b1;
    outp[(m + 1) * 256 + c + 0] = acc10 + b0;
    outp[(m + 1) * 256 + c + 1] = acc11 + b1;
}

// Pair phase: block = 16x16 (i,j) tile, one pair per thread.
__global__ __launch_bounds__(256) void pair_kernel(
    const double* __restrict__ ca_d, const double* __restrict__ cb_d,
    const float* __restrict__ sa_f, const float* __restrict__ sb_f,
    const double* __restrict__ cw2d, const float* __restrict__ cb2,
    const float* __restrict__ sw2, const float* __restrict__ sb2,
    float* __restrict__ out)
{
    const int bi = blockIdx.y, bj = blockIdx.x;
    if (bj < bi) return;                       // tile fully below diagonal
    const int i0 = bi * 16, j0 = bj * 16;
    const int t  = threadIdx.x;
    const int ti = t >> 4, tj = t & 15;
    const int i = i0 + ti, j = j0 + tj;
    const bool valid = (j > i);
    const int p = i * 511 - (i * (i - 1)) / 2 + (j - i - 1);

    __shared__ double smem[2 * 16 * 66];       // 16896 B, aliased by fp32 phase
    double* sXd = smem;
    double* sYd = smem + 16 * 66;
    float*  sXf = (float*)smem;
    float*  sYf = (float*)smem + 16 * 68;

    const int sr  = t >> 4;   // staging row 0..15
    const int skq = t & 15;   // staging quad 0..15

    // ---------- strength path (fp32) ----------
    float accs = 0.f;
    for (int k0 = 0; k0 < 256; k0 += 64) {
        float4 xa = *(const float4*)&sa_f[(i0 + sr) * 256 + k0 + skq * 4];
        float4 xb = *(const float4*)&sb_f[(j0 + sr) * 256 + k0 + skq * 4];
        __syncthreads();
        *(float4*)&sXf[sr * 68 + skq * 4] = xa;
        *(float4*)&sYf[sr * 68 + skq * 4] = xb;
        __syncthreads();
        #pragma unroll 16
        for (int kk = 0; kk < 64; ++kk) {
            float h = sXf[ti * 68 + kk] + sYf[tj * 68 + kk];  // sb1 folded into sa
            h = fmaxf(h, 0.f);
            accs = fmaf(h, sw2[k0 + kk], accs);               // sw2: scalar load
        }
        __syncthreads();
    }
    {
        float x = accs + sb2[0];
        float strength = 1.0f / (1.0f + expf(-x));
        if (valid) out[STRENGTH_OFF + p] = strength;
    }

    // ---------- classifier path (fp64 for argmax stability) ----------
    double lg[10];
    #pragma unroll
    for (int c = 0; c < 10; ++c) lg[c] = 0.0;

    for (int k0 = 0; k0 < 512; k0 += 64) {
        double2 xa0 = *(const double2*)&ca_d[(i0 + sr) * 512 + k0 + skq * 4];
        double2 xa1 = *(const double2*)&ca_d[(i0 + sr) * 512 + k0 + skq * 4 + 2];
        double2 xb0 = *(const double2*)&cb_d[(j0 + sr) * 512 + k0 + skq * 4];
        double2 xb1 = *(const double2*)&cb_d[(j0 + sr) * 512 + k0 + skq * 4 + 2];
        __syncthreads();
        *(double2*)&sXd[sr * 66 + skq * 4]     = xa0;
        *(double2*)&sXd[sr * 66 + skq * 4 + 2] = xa1;
        *(double2*)&sYd[sr * 66 + skq * 4]     = xb0;
        *(double2*)&sYd[sr * 66 + skq * 4 + 2] = xb1;
        __syncthreads();
        #pragma unroll 8
        for (int kk = 0; kk < 64; ++kk) {
            double h = sXd[ti * 66 + kk] + sYd[tj * 66 + kk];  // cb1 folded into ca
            h = fmax(h, 0.0);
            const double* w = &cw2d[(k0 + kk) * 10];           // uniform -> s_load
            #pragma unroll
            for (int c = 0; c < 10; ++c) lg[c] = fma(h, w[c], lg[c]);
        }
        __syncthreads();
    }

    // epilogue: bias, log_softmax, argmax
    #pragma unroll
    for (int c = 0; c < 10; ++c) lg[c] += (double)cb2[c];
    double mx = lg[0];
    #pragma unroll
    for (int c = 1; c < 10; ++c) mx = fmax(mx, lg[c]);
    double sum = 0.0;
    #pragma unroll
    for (int c = 0; c < 10; ++c) sum += exp(lg[c] - mx);
    double ls = mx + log(sum);
    int amax = 0; double best = lg[0];
    #pragma unroll
    for (int c = 1; c < 10; ++c) {
        if (lg[c] > best) { best = lg[c]; amax = c; }   // strict > == np first-max
    }
    if (valid) {
        float* tp = out + TYPES_OFF + p * 10;
        #pragma unroll
        for (int c = 0; c < 10; ++c) tp[c] = (float)(lg[c] - ls);
        out[ARGMAX_OFF + p] = (float)amax;
    }
}

extern "C" void kernel_launch(void* const* d_in, const int* in_sizes, int n_in,
                              void* d_out, int out_size, void* d_ws, size_t ws_size,
                              hipStream_t stream) {
    const float* F   = (const float*)d_in[0];
    const float* cw1 = (const float*)d_in[1];
    const float* cb1 = (const float*)d_in[2];
    const float* cw2 = (const float*)d_in[3];
    const float* cb2 = (const float*)d_in[4];
    const float* sw1 = (const float*)d_in[5];
    const float* sb1 = (const float*)d_in[6];
    const float* sw2 = (const float*)d_in[7];
    const float* sb2 = (const float*)d_in[8];
    float* out = (float*)d_out;

    char* ws = (char*)d_ws;
    double* ca_d = (double*)(ws);
    double* cb_d = (double*)(ws + 2097152);
    float*  sa_f = (float*)(ws + 4194304);
    float*  sb_f = (float*)(ws + 4718592);
    double* cw2d = (double*)(ws + 5242880);

    hipLaunchKernelGGL(cvt_cw2_kernel, dim3(20), dim3(256), 0, stream, cw2, cw2d);
    hipLaunchKernelGGL(proj_c_kernel, dim3(32, 16), dim3(256), 0, stream, F, cw1, cb1, ca_d, cb_d);
    hipLaunchKernelGGL(proj_s_kernel, dim3(16, 16), dim3(256), 0, stream, F, sw1, sb1, sa_f, sb_f);
    hipLaunchKernelGGL(pair_kernel, dim3(32, 32), dim3(256), 0, stream,
                       ca_d, cb_d, sa_f, sb_f, cw2d, cb2, sw2, sb2, out);
}